// Round 2
// baseline (723.824 us; speedup 1.0000x reference)
//
#include <hip/hip_runtime.h>
#include <hip/hip_bf16.h>
#include <math.h>

typedef __attribute__((ext_vector_type(8))) short bf16x8;
typedef __attribute__((ext_vector_type(4))) float f32x4;
typedef __attribute__((ext_vector_type(4))) short short4v;
typedef __attribute__((ext_vector_type(4))) int int4v;

__device__ __forceinline__ short f2bf(float f) {
  union { float f; unsigned u; } v; v.f = f;
  unsigned r = v.u + 0x7fffu + ((v.u >> 16) & 1u);
  return (short)(r >> 16);
}

// ---------------- conversion kernels ----------------

__global__ void convert_x_kernel(const float* __restrict__ x, short* __restrict__ xb, int n) {
  int i = (blockIdx.x * blockDim.x + threadIdx.x) * 4;
  int stride = gridDim.x * blockDim.x * 4;
  for (; i < n; i += stride) {
    float4 v = *(const float4*)(x + i);
    short4v o;
    o.x = f2bf(v.x); o.y = f2bf(v.y); o.z = f2bf(v.z); o.w = f2bf(v.w);
    *(short4v*)(xb + i) = o;
  }
}

// W [2048][6144] f32 -> Wt [6144][2048] bf16
__global__ void transpose_w_kernel(const float* __restrict__ W, short* __restrict__ Wt) {
  __shared__ short tile[32][33];
  int n0 = blockIdx.x * 32, k0 = blockIdx.y * 32;
  int tx = threadIdx.x, ty = threadIdx.y; // (32, 8)
#pragma unroll
  for (int u = 0; u < 4; ++u) {
    int k = k0 + ty + u * 8;
    tile[ty + u * 8][tx] = f2bf(W[(size_t)k * 6144 + n0 + tx]);
  }
  __syncthreads();
#pragma unroll
  for (int u = 0; u < 4; ++u) {
    int n = n0 + ty + u * 8;
    Wt[(size_t)n * 2048 + k0 + tx] = tile[tx][ty + u * 8];
  }
}

// Normalize mask to u8 0/1, detecting storage layout (bool-bytes / int32 / f32).
__global__ void mask_norm_kernel(const unsigned* __restrict__ m, unsigned char* __restrict__ out, int n) {
  __shared__ int flagA, flagB;
  if (threadIdx.x == 0) { flagA = 0; flagB = 0; }
  __syncthreads();
  int a = 0, b = 0;
  for (int i = threadIdx.x; i < n / 4; i += blockDim.x) {
    unsigned wv = m[i];
    if (wv > 1u) a = 1;
    if (wv != 0u && wv != 0x3f800000u) b = 1;
  }
  if (a) atomicOr(&flagA, 1);
  if (b) atomicOr(&flagB, 1);
  __syncthreads();
  int A = flagA, B = flagB;
  for (int i = threadIdx.x; i < n; i += blockDim.x) {
    unsigned char r;
    if (!A) r = (m[i] != 0u) ? 1 : 0;
    else if (!B) r = (((const float*)m)[i] != 0.f) ? 1 : 0;
    else r = (((const unsigned char*)m)[i] != 0) ? 1 : 0;
    out[i] = r;
  }
}

// ---------------- QKV GEMM (m97 structure) ----------------
// A: x bf16 [4096][2048]; Bt: Wt bf16 [6144][2048]; out: Q(prescaled),K [B,H,S,128] bf16, Vt [B,H,128,S] bf16

__global__ __launch_bounds__(256, 2) void qkv_gemm_kernel(
    const short* __restrict__ A, const short* __restrict__ Bt, const float* __restrict__ bias,
    short* __restrict__ qws, short* __restrict__ kws, short* __restrict__ vtws) {
  __shared__ short As[128 * 32];
  __shared__ short Bs[128 * 32];
  __shared__ short Vs[64 * 136];

  const int K = 2048;
  int lid = blockIdx.x;                     // 1536 blocks, 1536 % 8 == 0
  int swz = (lid & 7) * 192 + (lid >> 3);   // XCD-contiguous chunks
  int tm = swz / 48, tn = swz % 48;
  int m0 = tm * 128, n0 = tn * 128;
  int t = threadIdx.x, lane = t & 63, w = t >> 6;
  int wr = w >> 1, wc = w & 1;
  int g = lane >> 4, c = lane & 15;

  f32x4 acc[4][4] = {};

  for (int k0 = 0; k0 < K; k0 += 32) {
#pragma unroll
    for (int rep = 0; rep < 2; ++rep) {
      int chunk = rep * 256 + t;
      int row = chunk >> 2, cc = chunk & 3;
      const short* ga = A + (size_t)(m0 + row) * K + (k0 + cc * 8);
      __builtin_amdgcn_global_load_lds((const __attribute__((address_space(1))) void*)ga,
          (__attribute__((address_space(3))) void*)(As + chunk * 8), 16, 0, 0);
      const short* gb = Bt + (size_t)(n0 + row) * K + (k0 + cc * 8);
      __builtin_amdgcn_global_load_lds((const __attribute__((address_space(1))) void*)gb,
          (__attribute__((address_space(3))) void*)(Bs + chunk * 8), 16, 0, 0);
    }
    __syncthreads();
    bf16x8 ar[4], br[4];
#pragma unroll
    for (int i = 0; i < 4; ++i) ar[i] = *(const bf16x8*)(As + (wr * 64 + i * 16 + c) * 32 + g * 8);
#pragma unroll
    for (int j = 0; j < 4; ++j) br[j] = *(const bf16x8*)(Bs + (wc * 64 + j * 16 + c) * 32 + g * 8);
#pragma unroll
    for (int i = 0; i < 4; ++i)
#pragma unroll
      for (int j = 0; j < 4; ++j)
        acc[i][j] = __builtin_amdgcn_mfma_f32_16x16x32_bf16(ar[i], br[j], acc[i][j], 0, 0, 0);
    __syncthreads();
  }

  int sec = n0 >> 11;
  int h = (n0 >> 7) & 15;
  int b = m0 >> 11;
  int s0 = m0 & 2047;
  size_t bh = (size_t)(b * 16 + h);

  if (sec < 2) {
    short* dst = (sec == 0 ? qws : kws) + bh * (size_t)(2048 * 128);
    const float sc = (sec == 0) ? 0.08838834764831845f : 1.0f;  // fold hd^-0.5 into Q
#pragma unroll
    for (int i = 0; i < 4; ++i)
#pragma unroll
      for (int j = 0; j < 4; ++j) {
        int dcol = wc * 64 + j * 16 + c;
        float bv = bias[n0 + dcol];
#pragma unroll
        for (int r = 0; r < 4; ++r) {
          int srow = s0 + wr * 64 + i * 16 + g * 4 + r;
          dst[(size_t)srow * 128 + dcol] = f2bf((acc[i][j][r] + bv) * sc);
        }
      }
  } else {
    // V: transpose through LDS so Vt stores are coalesced along s
    short* dst = vtws + bh * (size_t)(128 * 2048);
#pragma unroll
    for (int hs = 0; hs < 2; ++hs) {
      if (wr == hs) {
#pragma unroll
        for (int i = 0; i < 4; ++i)
#pragma unroll
          for (int j = 0; j < 4; ++j) {
            int dcol = wc * 64 + j * 16 + c;
            float bv = bias[n0 + dcol];
#pragma unroll
            for (int r = 0; r < 4; ++r)
              Vs[(i * 16 + g * 4 + r) * 136 + dcol] = f2bf(acc[i][j][r] + bv);
          }
      }
      __syncthreads();
      {
        int d = t >> 1, sc2 = (t & 1) * 32;
        size_t off = (size_t)d * 2048 + s0 + hs * 64 + sc2;
#pragma unroll
        for (int q = 0; q < 4; ++q) {
          int4v pk;
#pragma unroll
          for (int e = 0; e < 4; ++e) {
            int u = q * 8 + e * 2;
            unsigned lo = (unsigned short)Vs[(sc2 + u) * 136 + d];
            unsigned hi = (unsigned short)Vs[(sc2 + u + 1) * 136 + d];
            pk[e] = (int)(lo | (hi << 16));
          }
          ((int4v*)(dst + off))[q] = pk;
        }
      }
      __syncthreads();
    }
  }
}

// ---------------- flash attention ----------------
// Q(prescaled),K: [B,H,S,128] bf16; Vt: [B,H,128,S] bf16; out: [B,S,H*128] f32
// 1024 blocks x 4 waves; 16 q-rows/wave; KVBLK=64; defer-max; deferred l-reduce.

__global__ __launch_bounds__(256, 4) void attn_kernel(
    const short* __restrict__ qws, const short* __restrict__ kws, const short* __restrict__ vtws,
    const unsigned char* __restrict__ maskb, float* __restrict__ out) {
  __shared__ short P[4][16 * 72];  // per-wave private P tile, stride 72 shorts
  const int S = 2048, HD = 128;
  int lid = blockIdx.x;                    // 1024 blocks
  int swz = (lid & 7) * 128 + (lid >> 3);  // 4 heads per XCD (KV L2 locality)
  int bh = swz >> 5, qblk = swz & 31;
  int b = bh >> 4, h = bh & 15;
  int t = threadIdx.x, lane = t & 63, w = t >> 6, g = lane >> 4, c = lane & 15;
  int q0 = qblk * 64 + w * 16;
  const short* Q = qws + (size_t)bh * S * HD;
  const short* Kp = kws + (size_t)bh * S * HD;
  const short* Vt = vtws + (size_t)bh * HD * S;
  const unsigned char* mk = maskb + b * S;
  const float NEG = -3.4028235e38f;

  bf16x8 qf[4];
#pragma unroll
  for (int kc = 0; kc < 4; ++kc)
    qf[kc] = *(const bf16x8*)(Q + (size_t)(q0 + c) * HD + kc * 32 + g * 8);

  f32x4 acc[8] = {};
  float m_[4], lp[4];
#pragma unroll
  for (int i = 0; i < 4; ++i) { m_[i] = -INFINITY; lp[i] = 0.f; }

  short* pl = &P[w][0];

  for (int kv0 = 0; kv0 < S; kv0 += 64) {
    float p[4][4];
#pragma unroll
    for (int ch = 0; ch < 2; ++ch) {
      bf16x8 kf[2][4];
#pragma unroll
      for (int nb = 0; nb < 2; ++nb)
#pragma unroll
        for (int kc = 0; kc < 4; ++kc)
          kf[nb][kc] = *(const bf16x8*)(Kp + (size_t)(kv0 + ch * 32 + nb * 16 + c) * HD + kc * 32 + g * 8);
      f32x4 sv[2] = {};
      __builtin_amdgcn_s_setprio(1);
#pragma unroll
      for (int nb = 0; nb < 2; ++nb)
#pragma unroll
        for (int kc = 0; kc < 4; ++kc)
          sv[nb] = __builtin_amdgcn_mfma_f32_16x16x32_bf16(qf[kc], kf[nb][kc], sv[nb], 0, 0, 0);
      __builtin_amdgcn_s_setprio(0);
#pragma unroll
      for (int nb = 0; nb < 2; ++nb) {
        bool keep = mk[kv0 + ch * 32 + nb * 16 + c] != 0;
#pragma unroll
        for (int i = 0; i < 4; ++i)
          p[ch * 2 + nb][i] = keep ? sv[nb][i] : NEG;
      }
    }

    // row max (lane-local over 4 nb, then 16-lane shuffle tree)
    float rmax[4];
#pragma unroll
    for (int i = 0; i < 4; ++i)
      rmax[i] = fmaxf(fmaxf(p[0][i], p[1][i]), fmaxf(p[2][i], p[3][i]));
#pragma unroll
    for (int d = 1; d < 16; d <<= 1)
#pragma unroll
      for (int i = 0; i < 4; ++i) rmax[i] = fmaxf(rmax[i], __shfl_xor(rmax[i], d));

    // defer-max: only rescale when a row max grew by > 8
    bool need = (rmax[0] > m_[0] + 8.f) || (rmax[1] > m_[1] + 8.f) ||
                (rmax[2] > m_[2] + 8.f) || (rmax[3] > m_[3] + 8.f);
    if (__any(need)) {
#pragma unroll
      for (int i = 0; i < 4; ++i) {
        float mn = fmaxf(m_[i], rmax[i]);
        float al = __expf(m_[i] - mn);
        m_[i] = mn; lp[i] *= al;
#pragma unroll
        for (int db = 0; db < 8; ++db) acc[db][i] *= al;
      }
    }

    // exp + per-lane partial l + P write (bf16)
#pragma unroll
    for (int nb4 = 0; nb4 < 4; ++nb4)
#pragma unroll
      for (int i = 0; i < 4; ++i) {
        float e = __expf(p[nb4][i] - m_[i]);
        lp[i] += e;
        pl[(g * 4 + i) * 72 + nb4 * 16 + c] = f2bf(e);
      }

    // PV (same-wave LDS: in-order, no barrier)
#pragma unroll
    for (int ch = 0; ch < 2; ++ch) {
      bf16x8 pf = *(const bf16x8*)(pl + c * 72 + ch * 32 + g * 8);
      __builtin_amdgcn_s_setprio(1);
#pragma unroll
      for (int db = 0; db < 8; ++db) {
        bf16x8 vf = *(const bf16x8*)(Vt + (size_t)(db * 16 + c) * S + kv0 + ch * 32 + g * 8);
        acc[db] = __builtin_amdgcn_mfma_f32_16x16x32_bf16(pf, vf, acc[db], 0, 0, 0);
      }
      __builtin_amdgcn_s_setprio(0);
    }
  }

  // final l reduce + output
#pragma unroll
  for (int d = 1; d < 16; d <<= 1)
#pragma unroll
    for (int i = 0; i < 4; ++i) lp[i] += __shfl_xor(lp[i], d);
  float inv[4];
#pragma unroll
  for (int i = 0; i < 4; ++i) inv[i] = 1.f / lp[i];
#pragma unroll
  for (int db = 0; db < 8; ++db)
#pragma unroll
    for (int i = 0; i < 4; ++i) {
      int srow = q0 + g * 4 + i;
      out[((size_t)(b * 2048 + srow)) * 2048 + h * 128 + db * 16 + c] = acc[db][i] * inv[i];
    }
}

// ---------------- launch ----------------

extern "C" void kernel_launch(void* const* d_in, const int* in_sizes, int n_in,
                              void* d_out, int out_size, void* d_ws, size_t ws_size,
                              hipStream_t stream) {
  const float* x = (const float*)d_in[0];
  const float* W = (const float*)d_in[1];
  const float* bias = (const float*)d_in[2];
  const void* mask = d_in[3];
  float* out = (float*)d_out;

  char* ws = (char*)d_ws;
  short* xb = (short*)(ws);
  short* wt = (short*)(ws + 16777216);
  short* qws = (short*)(ws + 41943040);
  short* kws = (short*)(ws + 58720256);
  short* vtws = (short*)(ws + 75497472);
  unsigned char* maskb = (unsigned char*)(ws + 92274688);

  convert_x_kernel<<<dim3(2048), dim3(256), 0, stream>>>(x, xb, 2 * 2048 * 2048);
  transpose_w_kernel<<<dim3(192, 64), dim3(32, 8), 0, stream>>>(W, wt);
  mask_norm_kernel<<<dim3(1), dim3(256), 0, stream>>>((const unsigned*)mask, maskb, 2 * 2048);
  qkv_gemm_kernel<<<dim3(1536), dim3(256), 0, stream>>>(xb, wt, bias, qws, kws, vtws);
  attn_kernel<<<dim3(1024), dim3(256), 0, stream>>>(qws, kws, vtws, maskb, out);
}

// Round 3
// 427.388 us; speedup vs baseline: 1.6936x; 1.6936x over previous
//
#include <hip/hip_runtime.h>
#include <hip/hip_bf16.h>
#include <math.h>

typedef __attribute__((ext_vector_type(8))) short bf16x8;
typedef __attribute__((ext_vector_type(4))) float f32x4;
typedef __attribute__((ext_vector_type(4))) short short4v;
typedef __attribute__((ext_vector_type(4))) int int4v;

__device__ __forceinline__ short f2bf(float f) {
  union { float f; unsigned u; } v; v.f = f;
  unsigned r = v.u + 0x7fffu + ((v.u >> 16) & 1u);
  return (short)(r >> 16);
}

// ---------------- conversion kernels ----------------

__global__ void convert_x_kernel(const float* __restrict__ x, short* __restrict__ xb, int n) {
  int i = (blockIdx.x * blockDim.x + threadIdx.x) * 4;
  int stride = gridDim.x * blockDim.x * 4;
  for (; i < n; i += stride) {
    float4 v = *(const float4*)(x + i);
    short4v o;
    o.x = f2bf(v.x); o.y = f2bf(v.y); o.z = f2bf(v.z); o.w = f2bf(v.w);
    *(short4v*)(xb + i) = o;
  }
}

// W [2048][6144] f32 -> Wt [6144][2048] bf16
__global__ void transpose_w_kernel(const float* __restrict__ W, short* __restrict__ Wt) {
  __shared__ short tile[32][33];
  int n0 = blockIdx.x * 32, k0 = blockIdx.y * 32;
  int tx = threadIdx.x, ty = threadIdx.y; // (32, 8)
#pragma unroll
  for (int u = 0; u < 4; ++u) {
    int k = k0 + ty + u * 8;
    tile[ty + u * 8][tx] = f2bf(W[(size_t)k * 6144 + n0 + tx]);
  }
  __syncthreads();
#pragma unroll
  for (int u = 0; u < 4; ++u) {
    int n = n0 + ty + u * 8;
    Wt[(size_t)n * 2048 + k0 + tx] = tile[tx][ty + u * 8];
  }
}

// Normalize mask to u8 0/1, detecting storage layout (bool-bytes / int32 / f32).
__global__ void mask_norm_kernel(const unsigned* __restrict__ m, unsigned char* __restrict__ out, int n) {
  __shared__ int flagA, flagB;
  if (threadIdx.x == 0) { flagA = 0; flagB = 0; }
  __syncthreads();
  int a = 0, b = 0;
  for (int i = threadIdx.x; i < n / 4; i += blockDim.x) {
    unsigned wv = m[i];
    if (wv > 1u) a = 1;
    if (wv != 0u && wv != 0x3f800000u) b = 1;
  }
  if (a) atomicOr(&flagA, 1);
  if (b) atomicOr(&flagB, 1);
  __syncthreads();
  int A = flagA, B = flagB;
  for (int i = threadIdx.x; i < n; i += blockDim.x) {
    unsigned char r;
    if (!A) r = (m[i] != 0u) ? 1 : 0;
    else if (!B) r = (((const float*)m)[i] != 0.f) ? 1 : 0;
    else r = (((const unsigned char*)m)[i] != 0) ? 1 : 0;
    out[i] = r;
  }
}

// ---------------- QKV GEMM (m97 structure) ----------------

__global__ __launch_bounds__(256, 2) void qkv_gemm_kernel(
    const short* __restrict__ A, const short* __restrict__ Bt, const float* __restrict__ bias,
    short* __restrict__ qws, short* __restrict__ kws, short* __restrict__ vtws) {
  __shared__ short As[128 * 32];
  __shared__ short Bs[128 * 32];
  __shared__ short Vs[64 * 136];

  const int K = 2048;
  int lid = blockIdx.x;                     // 1536 blocks
  int swz = (lid & 7) * 192 + (lid >> 3);
  int tm = swz / 48, tn = swz % 48;
  int m0 = tm * 128, n0 = tn * 128;
  int t = threadIdx.x, lane = t & 63, w = t >> 6;
  int wr = w >> 1, wc = w & 1;
  int g = lane >> 4, c = lane & 15;

  f32x4 acc[4][4] = {};

  for (int k0 = 0; k0 < K; k0 += 32) {
#pragma unroll
    for (int rep = 0; rep < 2; ++rep) {
      int chunk = rep * 256 + t;
      int row = chunk >> 2, cc = chunk & 3;
      const short* ga = A + (size_t)(m0 + row) * K + (k0 + cc * 8);
      __builtin_amdgcn_global_load_lds((const __attribute__((address_space(1))) void*)ga,
          (__attribute__((address_space(3))) void*)(As + chunk * 8), 16, 0, 0);
      const short* gb = Bt + (size_t)(n0 + row) * K + (k0 + cc * 8);
      __builtin_amdgcn_global_load_lds((const __attribute__((address_space(1))) void*)gb,
          (__attribute__((address_space(3))) void*)(Bs + chunk * 8), 16, 0, 0);
    }
    __syncthreads();
    bf16x8 ar[4], br[4];
#pragma unroll
    for (int i = 0; i < 4; ++i) ar[i] = *(const bf16x8*)(As + (wr * 64 + i * 16 + c) * 32 + g * 8);
#pragma unroll
    for (int j = 0; j < 4; ++j) br[j] = *(const bf16x8*)(Bs + (wc * 64 + j * 16 + c) * 32 + g * 8);
#pragma unroll
    for (int i = 0; i < 4; ++i)
#pragma unroll
      for (int j = 0; j < 4; ++j)
        acc[i][j] = __builtin_amdgcn_mfma_f32_16x16x32_bf16(ar[i], br[j], acc[i][j], 0, 0, 0);
    __syncthreads();
  }

  int sec = n0 >> 11;
  int h = (n0 >> 7) & 15;
  int b = m0 >> 11;
  int s0 = m0 & 2047;
  size_t bh = (size_t)(b * 16 + h);

  if (sec < 2) {
    short* dst = (sec == 0 ? qws : kws) + bh * (size_t)(2048 * 128);
    const float sc = (sec == 0) ? 0.08838834764831845f : 1.0f;
#pragma unroll
    for (int i = 0; i < 4; ++i)
#pragma unroll
      for (int j = 0; j < 4; ++j) {
        int dcol = wc * 64 + j * 16 + c;
        float bv = bias[n0 + dcol];
#pragma unroll
        for (int r = 0; r < 4; ++r) {
          int srow = s0 + wr * 64 + i * 16 + g * 4 + r;
          dst[(size_t)srow * 128 + dcol] = f2bf((acc[i][j][r] + bv) * sc);
        }
      }
  } else {
    short* dst = vtws + bh * (size_t)(128 * 2048);
#pragma unroll
    for (int hs = 0; hs < 2; ++hs) {
      if (wr == hs) {
#pragma unroll
        for (int i = 0; i < 4; ++i)
#pragma unroll
          for (int j = 0; j < 4; ++j) {
            int dcol = wc * 64 + j * 16 + c;
            float bv = bias[n0 + dcol];
#pragma unroll
            for (int r = 0; r < 4; ++r)
              Vs[(i * 16 + g * 4 + r) * 136 + dcol] = f2bf(acc[i][j][r] + bv);
          }
      }
      __syncthreads();
      {
        int d = t >> 1, sc2 = (t & 1) * 32;
        size_t off = (size_t)d * 2048 + s0 + hs * 64 + sc2;
#pragma unroll
        for (int q = 0; q < 4; ++q) {
          int4v pk;
#pragma unroll
          for (int e = 0; e < 4; ++e) {
            int u = q * 8 + e * 2;
            unsigned lo = (unsigned short)Vs[(sc2 + u) * 136 + d];
            unsigned hi = (unsigned short)Vs[(sc2 + u + 1) * 136 + d];
            pk[e] = (int)(lo | (hi << 16));
          }
          ((int4v*)(dst + off))[q] = pk;
        }
      }
      __syncthreads();
    }
  }
}

// ---------------- flash attention ----------------
// Q(prescaled),K: [B,H,S,128] bf16; Vt: [B,H,128,S] bf16; out: [B,S,H*128] f32
// 512 blocks x 4 waves x 32 q-rows. KVBLK=32, K/V staged in LDS (double-buffered,
// XOR-swizzled, global_load_lds), defer-max, deferred l-reduce.

__global__ __launch_bounds__(256, 2) void attn_kernel(
    const short* __restrict__ qws, const short* __restrict__ kws, const short* __restrict__ vtws,
    const unsigned char* __restrict__ maskb, float* __restrict__ out) {
  __shared__ short Ks[2][32 * 128];   // [kv 32][d 128], chunk ^= (row&7)
  __shared__ short Vs[2][128 * 32];   // [d 128][kv 32], chunk ^= ((row>>1)&3)
  __shared__ short P[4][32 * 40];     // per-wave [q 32][kv 32+pad]
  __shared__ unsigned char msk[2048];

  const int S = 2048, HD = 128;
  int lid = blockIdx.x;                    // 512 blocks
  int swz = (lid & 7) * 64 + (lid >> 3);
  int bh = swz >> 4, qblk = swz & 15;
  int b = bh >> 4, h = bh & 15;
  int t = threadIdx.x, lane = t & 63, w = t >> 6, g = lane >> 4, c = lane & 15;
  int q0 = qblk * 128 + w * 32;
  const short* Q = qws + (size_t)bh * S * HD;
  const short* Kp = kws + (size_t)bh * S * HD;
  const short* Vt = vtws + (size_t)bh * HD * S;
  const unsigned char* mk = maskb + b * S;
  const float NEG = -3.4028235e38f;

  // stage helper (inlined twice below): K tile 32x128 (512 16B-chunks),
  // V tile 128x32 (512 chunks); 2 gload rounds each.
#define STAGE_KV(buf, kv0_)                                                              \
  {                                                                                      \
    _Pragma("unroll")                                                                    \
    for (int rr = 0; rr < 2; ++rr) {                                                     \
      int ci = rr * 256 + t;                                                             \
      int r = ci >> 4, cin = ci & 15;                                                    \
      const short* gk = Kp + (size_t)((kv0_) + r) * HD + ((cin ^ (r & 7)) * 8);          \
      __builtin_amdgcn_global_load_lds((const __attribute__((address_space(1))) void*)gk,\
          (__attribute__((address_space(3))) void*)(&Ks[buf][0] + ci * 8), 16, 0, 0);    \
    }                                                                                    \
    _Pragma("unroll")                                                                    \
    for (int rr = 0; rr < 2; ++rr) {                                                     \
      int ci = rr * 256 + t;                                                             \
      int r = ci >> 2, cin = ci & 3;                                                     \
      const short* gv = Vt + (size_t)r * S + (kv0_) + ((cin ^ ((r >> 1) & 3)) * 8);      \
      __builtin_amdgcn_global_load_lds((const __attribute__((address_space(1))) void*)gv,\
          (__attribute__((address_space(3))) void*)(&Vs[buf][0] + ci * 8), 16, 0, 0);    \
    }                                                                                    \
  }

  // Q fragments (global, L2-hot)
  bf16x8 qf[2][4];
#pragma unroll
  for (int rb = 0; rb < 2; ++rb)
#pragma unroll
    for (int kc = 0; kc < 4; ++kc)
      qf[rb][kc] = *(const bf16x8*)(Q + (size_t)(q0 + rb * 16 + c) * HD + kc * 32 + g * 8);

  // mask row -> LDS
  *(int2*)(msk + t * 8) = *(const int2*)(mk + t * 8);

  STAGE_KV(0, 0);
  __syncthreads();   // drains vmcnt(0)+lgkmcnt(0)

  f32x4 acc[2][8] = {};
  float m_[2][4], lp[2][4];
#pragma unroll
  for (int rb = 0; rb < 2; ++rb)
#pragma unroll
    for (int i = 0; i < 4; ++i) { m_[rb][i] = -INFINITY; lp[rb][i] = 0.f; }

  short* pl = &P[w][0];
  int cur = 0;

  for (int it = 0; it < 64; ++it) {
    int kv0 = it * 32;
    if (it + 1 < 64) STAGE_KV(cur ^ 1, kv0 + 32);

    const short* ks = &Ks[cur][0];
    const short* vs = &Vs[cur][0];

    // K fragments from swizzled LDS
    bf16x8 kf[2][4];
#pragma unroll
    for (int nb = 0; nb < 2; ++nb) {
      int row = nb * 16 + c;
#pragma unroll
      for (int kc = 0; kc < 4; ++kc)
        kf[nb][kc] = *(const bf16x8*)(ks + row * 128 + (((kc * 4 + g) ^ (row & 7)) * 8));
    }

    f32x4 sv[2][2] = {};
    __builtin_amdgcn_s_setprio(1);
#pragma unroll
    for (int rb = 0; rb < 2; ++rb)
#pragma unroll
      for (int nb = 0; nb < 2; ++nb)
#pragma unroll
        for (int kc = 0; kc < 4; ++kc)
          sv[rb][nb] = __builtin_amdgcn_mfma_f32_16x16x32_bf16(qf[rb][kc], kf[nb][kc], sv[rb][nb], 0, 0, 0);
    __builtin_amdgcn_s_setprio(0);

    bool keep[2];
#pragma unroll
    for (int nb = 0; nb < 2; ++nb) keep[nb] = (msk[kv0 + nb * 16 + c] != 0);

    float p_[2][2][4];
#pragma unroll
    for (int rb = 0; rb < 2; ++rb)
#pragma unroll
      for (int nb = 0; nb < 2; ++nb)
#pragma unroll
        for (int i = 0; i < 4; ++i)
          p_[rb][nb][i] = keep[nb] ? sv[rb][nb][i] : NEG;

    // row max
    float rmax[2][4];
#pragma unroll
    for (int rb = 0; rb < 2; ++rb)
#pragma unroll
      for (int i = 0; i < 4; ++i) rmax[rb][i] = fmaxf(p_[rb][0][i], p_[rb][1][i]);
#pragma unroll
    for (int d = 1; d < 16; d <<= 1)
#pragma unroll
      for (int rb = 0; rb < 2; ++rb)
#pragma unroll
        for (int i = 0; i < 4; ++i) rmax[rb][i] = fmaxf(rmax[rb][i], __shfl_xor(rmax[rb][i], d));

    bool need = false;
#pragma unroll
    for (int rb = 0; rb < 2; ++rb)
#pragma unroll
      for (int i = 0; i < 4; ++i) need = need || (rmax[rb][i] > m_[rb][i] + 8.f);
    if (__any(need)) {
#pragma unroll
      for (int rb = 0; rb < 2; ++rb)
#pragma unroll
        for (int i = 0; i < 4; ++i) {
          float mn = fmaxf(m_[rb][i], rmax[rb][i]);
          float al = __expf(m_[rb][i] - mn);
          m_[rb][i] = mn; lp[rb][i] *= al;
#pragma unroll
          for (int db = 0; db < 8; ++db) acc[rb][db][i] *= al;
        }
    }

    // exp + partial l + P write
#pragma unroll
    for (int rb = 0; rb < 2; ++rb)
#pragma unroll
      for (int nb = 0; nb < 2; ++nb)
#pragma unroll
        for (int i = 0; i < 4; ++i) {
          float e = __expf(p_[rb][nb][i] - m_[rb][i]);
          lp[rb][i] += e;
          pl[(rb * 16 + g * 4 + i) * 40 + nb * 16 + c] = f2bf(e);
        }

    // PV: P from per-wave LDS (same-wave in-order), V from swizzled LDS
    bf16x8 pf[2];
#pragma unroll
    for (int rb = 0; rb < 2; ++rb)
      pf[rb] = *(const bf16x8*)(pl + (rb * 16 + c) * 40 + g * 8);

    __builtin_amdgcn_s_setprio(1);
#pragma unroll
    for (int db = 0; db < 8; ++db) {
      int row = db * 16 + c;
      bf16x8 vf = *(const bf16x8*)(vs + row * 32 + ((g ^ ((row >> 1) & 3)) * 8));
#pragma unroll
      for (int rb = 0; rb < 2; ++rb)
        acc[rb][db] = __builtin_amdgcn_mfma_f32_16x16x32_bf16(pf[rb], vf, acc[rb][db], 0, 0, 0);
    }
    __builtin_amdgcn_s_setprio(0);

    __syncthreads();  // drains prefetch vmcnt + syncs buffer swap
    cur ^= 1;
  }

  // final l reduce + output
#pragma unroll
  for (int d = 1; d < 16; d <<= 1)
#pragma unroll
    for (int rb = 0; rb < 2; ++rb)
#pragma unroll
      for (int i = 0; i < 4; ++i) lp[rb][i] += __shfl_xor(lp[rb][i], d);
#pragma unroll
  for (int rb = 0; rb < 2; ++rb) {
    float inv[4];
#pragma unroll
    for (int i = 0; i < 4; ++i) inv[i] = 1.f / lp[rb][i];
#pragma unroll
    for (int db = 0; db < 8; ++db)
#pragma unroll
      for (int i = 0; i < 4; ++i) {
        int srow = q0 + rb * 16 + g * 4 + i;
        out[((size_t)(b * 2048 + srow)) * 2048 + h * 128 + db * 16 + c] = acc[rb][db][i] * inv[i];
      }
  }
#undef STAGE_KV
}

// ---------------- launch ----------------

extern "C" void kernel_launch(void* const* d_in, const int* in_sizes, int n_in,
                              void* d_out, int out_size, void* d_ws, size_t ws_size,
                              hipStream_t stream) {
  const float* x = (const float*)d_in[0];
  const float* W = (const float*)d_in[1];
  const float* bias = (const float*)d_in[2];
  const void* mask = d_in[3];
  float* out = (float*)d_out;

  char* ws = (char*)d_ws;
  short* xb = (short*)(ws);
  short* wt = (short*)(ws + 16777216);
  short* qws = (short*)(ws + 41943040);
  short* kws = (short*)(ws + 58720256);
  short* vtws = (short*)(ws + 75497472);
  unsigned char* maskb = (unsigned char*)(ws + 92274688);

  convert_x_kernel<<<dim3(2048), dim3(256), 0, stream>>>(x, xb, 2 * 2048 * 2048);
  transpose_w_kernel<<<dim3(192, 64), dim3(32, 8), 0, stream>>>(W, wt);
  mask_norm_kernel<<<dim3(1), dim3(256), 0, stream>>>((const unsigned*)mask, maskb, 2 * 2048);
  qkv_gemm_kernel<<<dim3(1536), dim3(256), 0, stream>>>(xb, wt, bias, qws, kws, vtws);
  attn_kernel<<<dim3(512), dim3(256), 0, stream>>>(qws, kws, vtws, maskb, out);
}

// Round 4
// 373.465 us; speedup vs baseline: 1.9381x; 1.1444x over previous
//
#include <hip/hip_runtime.h>
#include <hip/hip_bf16.h>
#include <math.h>

typedef __attribute__((ext_vector_type(8))) short bf16x8;
typedef __attribute__((ext_vector_type(4))) float f32x4;
typedef __attribute__((ext_vector_type(16))) float f32x16;
typedef __attribute__((ext_vector_type(4))) short short4v;
typedef __attribute__((ext_vector_type(4))) int int4v;

__device__ __forceinline__ short f2bf(float f) {
  union { float f; unsigned u; } v; v.f = f;
  unsigned r = v.u + 0x7fffu + ((v.u >> 16) & 1u);
  return (short)(r >> 16);
}

__device__ __forceinline__ unsigned cvt_pk_bf16(float lo, float hi) {
  unsigned r;
  asm volatile("v_cvt_pk_bf16_f32 %0, %1, %2" : "=v"(r) : "v"(lo), "v"(hi));
  return r;
}

// ---------------- conversion kernels ----------------

__global__ void convert_x_kernel(const float* __restrict__ x, short* __restrict__ xb, int n) {
  int i = (blockIdx.x * blockDim.x + threadIdx.x) * 4;
  int stride = gridDim.x * blockDim.x * 4;
  for (; i < n; i += stride) {
    float4 v = *(const float4*)(x + i);
    short4v o;
    o.x = f2bf(v.x); o.y = f2bf(v.y); o.z = f2bf(v.z); o.w = f2bf(v.w);
    *(short4v*)(xb + i) = o;
  }
}

// W [2048][6144] f32 -> Wt [6144][2048] bf16
__global__ void transpose_w_kernel(const float* __restrict__ W, short* __restrict__ Wt) {
  __shared__ short tile[32][33];
  int n0 = blockIdx.x * 32, k0 = blockIdx.y * 32;
  int tx = threadIdx.x, ty = threadIdx.y; // (32, 8)
#pragma unroll
  for (int u = 0; u < 4; ++u) {
    int k = k0 + ty + u * 8;
    tile[ty + u * 8][tx] = f2bf(W[(size_t)k * 6144 + n0 + tx]);
  }
  __syncthreads();
#pragma unroll
  for (int u = 0; u < 4; ++u) {
    int n = n0 + ty + u * 8;
    Wt[(size_t)n * 2048 + k0 + tx] = tile[tx][ty + u * 8];
  }
}

// Normalize mask to u8 0/1, detecting storage layout (bool-bytes / int32 / f32).
__global__ void mask_norm_kernel(const unsigned* __restrict__ m, unsigned char* __restrict__ out, int n) {
  __shared__ int flagA, flagB;
  if (threadIdx.x == 0) { flagA = 0; flagB = 0; }
  __syncthreads();
  int a = 0, b = 0;
  for (int i = threadIdx.x; i < n / 4; i += blockDim.x) {
    unsigned wv = m[i];
    if (wv > 1u) a = 1;
    if (wv != 0u && wv != 0x3f800000u) b = 1;
  }
  if (a) atomicOr(&flagA, 1);
  if (b) atomicOr(&flagB, 1);
  __syncthreads();
  int A = flagA, B = flagB;
  for (int i = threadIdx.x; i < n; i += blockDim.x) {
    unsigned char r;
    if (!A) r = (m[i] != 0u) ? 1 : 0;
    else if (!B) r = (((const float*)m)[i] != 0.f) ? 1 : 0;
    else r = (((const unsigned char*)m)[i] != 0) ? 1 : 0;
    out[i] = r;
  }
}

// ---------------- QKV GEMM (m97 structure; Vs unioned with As/Bs; 3 blocks/CU) --

__global__ __launch_bounds__(256, 3) void qkv_gemm_kernel(
    const short* __restrict__ A, const short* __restrict__ Bt, const float* __restrict__ bias,
    short* __restrict__ qws, short* __restrict__ kws, short* __restrict__ vtws) {
  // union: main-loop As(8KB)+Bs(8KB) overlap epilogue Vs(17.4KB)
  __shared__ __align__(16) char smem[17408];
  short* As = (short*)smem;
  short* Bs = (short*)(smem + 8192);
  short* Vs = (short*)smem;

  const int K = 2048;
  int lid = blockIdx.x;                     // 1536 blocks
  int swz = (lid & 7) * 192 + (lid >> 3);
  int tm = swz / 48, tn = swz % 48;
  int m0 = tm * 128, n0 = tn * 128;
  int t = threadIdx.x, lane = t & 63, w = t >> 6;
  int wr = w >> 1, wc = w & 1;
  int g = lane >> 4, c = lane & 15;

  f32x4 acc[4][4] = {};

  for (int k0 = 0; k0 < K; k0 += 32) {
#pragma unroll
    for (int rep = 0; rep < 2; ++rep) {
      int chunk = rep * 256 + t;
      int row = chunk >> 2, cc = chunk & 3;
      const short* ga = A + (size_t)(m0 + row) * K + (k0 + cc * 8);
      __builtin_amdgcn_global_load_lds((const __attribute__((address_space(1))) void*)ga,
          (__attribute__((address_space(3))) void*)(As + chunk * 8), 16, 0, 0);
      const short* gb = Bt + (size_t)(n0 + row) * K + (k0 + cc * 8);
      __builtin_amdgcn_global_load_lds((const __attribute__((address_space(1))) void*)gb,
          (__attribute__((address_space(3))) void*)(Bs + chunk * 8), 16, 0, 0);
    }
    __syncthreads();
    bf16x8 ar[4], br[4];
#pragma unroll
    for (int i = 0; i < 4; ++i) ar[i] = *(const bf16x8*)(As + (wr * 64 + i * 16 + c) * 32 + g * 8);
#pragma unroll
    for (int j = 0; j < 4; ++j) br[j] = *(const bf16x8*)(Bs + (wc * 64 + j * 16 + c) * 32 + g * 8);
#pragma unroll
    for (int i = 0; i < 4; ++i)
#pragma unroll
      for (int j = 0; j < 4; ++j)
        acc[i][j] = __builtin_amdgcn_mfma_f32_16x16x32_bf16(ar[i], br[j], acc[i][j], 0, 0, 0);
    __syncthreads();
  }

  int sec = n0 >> 11;
  int h = (n0 >> 7) & 15;
  int b = m0 >> 11;
  int s0 = m0 & 2047;
  size_t bh = (size_t)(b * 16 + h);

  if (sec < 2) {
    short* dst = (sec == 0 ? qws : kws) + bh * (size_t)(2048 * 128);
    // Q prescale: hd^-0.5 * log2(e)  (attn works in exp2 domain)
    const float sc = (sec == 0) ? (0.08838834764831845f * 1.4426950408889634f) : 1.0f;
#pragma unroll
    for (int i = 0; i < 4; ++i)
#pragma unroll
      for (int j = 0; j < 4; ++j) {
        int dcol = wc * 64 + j * 16 + c;
        float bv = bias[n0 + dcol];
#pragma unroll
        for (int r = 0; r < 4; ++r) {
          int srow = s0 + wr * 64 + i * 16 + g * 4 + r;
          dst[(size_t)srow * 128 + dcol] = f2bf((acc[i][j][r] + bv) * sc);
        }
      }
  } else {
    short* dst = vtws + bh * (size_t)(128 * 2048);
#pragma unroll
    for (int hs = 0; hs < 2; ++hs) {
      if (wr == hs) {
#pragma unroll
        for (int i = 0; i < 4; ++i)
#pragma unroll
          for (int j = 0; j < 4; ++j) {
            int dcol = wc * 64 + j * 16 + c;
            float bv = bias[n0 + dcol];
#pragma unroll
            for (int r = 0; r < 4; ++r)
              Vs[(i * 16 + g * 4 + r) * 136 + dcol] = f2bf(acc[i][j][r] + bv);
          }
      }
      __syncthreads();
      {
        int d = t >> 1, sc2 = (t & 1) * 32;
        size_t off = (size_t)d * 2048 + s0 + hs * 64 + sc2;
#pragma unroll
        for (int q = 0; q < 4; ++q) {
          int4v pk;
#pragma unroll
          for (int e = 0; e < 4; ++e) {
            int u = q * 8 + e * 2;
            unsigned lo = (unsigned short)Vs[(sc2 + u) * 136 + d];
            unsigned hi = (unsigned short)Vs[(sc2 + u + 1) * 136 + d];
            pk[e] = (int)(lo | (hi << 16));
          }
          ((int4v*)(dst + off))[q] = pk;
        }
      }
      __syncthreads();
    }
  }
}

// ---------------- flash attention (swapped-operand 32x32x16) ----------------
// Q(prescaled by hd^-0.5*log2e),K: [B,H,S,128] bf16; Vt: [B,H,128,S] bf16; out f32.
// sv = mfma(K,Q): D[col=q=lane&31][row=k_local]; acc = mfma(Vt,P^T): D[col=q][row=d].
// Per-lane scalar softmax state (one q per lane). exp2 domain. Defer-max thr 12.

__global__ __launch_bounds__(256, 2) void attn_kernel(
    const short* __restrict__ qws, const short* __restrict__ kws, const short* __restrict__ vtws,
    const unsigned char* __restrict__ maskb, float* __restrict__ out) {
  __shared__ short Ks[2][32 * 128];   // [kv 32][d 128], chunk ^= (row&7)
  __shared__ short Vs[2][128 * 32];   // [d 128][kv 32], chunk ^= ((row>>1)&3)
  __shared__ short P[4][32 * 40];     // per-wave [q 32][kv 32 + pad], stride 40 shorts
  __shared__ float biasLds[2048];
  __shared__ int flagsLds[64];

  const int S = 2048, HD = 128;
  int lid = blockIdx.x;                    // 512 blocks
  int swz = (lid & 7) * 64 + (lid >> 3);
  int bh = swz >> 4, qblk = swz & 15;
  int b = bh >> 4, h = bh & 15;
  int t = threadIdx.x, lane = t & 63, w = t >> 6;
  int ql = lane & 31, hi = lane >> 5;
  int q0 = qblk * 128 + w * 32;
  const short* Q = qws + (size_t)bh * S * HD;
  const short* Kp = kws + (size_t)bh * S * HD;
  const short* Vt = vtws + (size_t)bh * HD * S;
  const unsigned char* mk = maskb + b * S;
  const float NEG = -3.4028235e38f;

#define STAGE_KV(buf, kv0_)                                                              \
  {                                                                                      \
    _Pragma("unroll")                                                                    \
    for (int rr = 0; rr < 2; ++rr) {                                                     \
      int ci = rr * 256 + t;                                                             \
      int r = ci >> 4, cin = ci & 15;                                                    \
      const short* gk = Kp + (size_t)((kv0_) + r) * HD + ((cin ^ (r & 7)) * 8);          \
      __builtin_amdgcn_global_load_lds((const __attribute__((address_space(1))) void*)gk,\
          (__attribute__((address_space(3))) void*)(&Ks[buf][0] + ci * 8), 16, 0, 0);    \
    }                                                                                    \
    _Pragma("unroll")                                                                    \
    for (int rr = 0; rr < 2; ++rr) {                                                     \
      int ci = rr * 256 + t;                                                             \
      int r = ci >> 2, cin = ci & 3;                                                     \
      const short* gv = Vt + (size_t)r * S + (kv0_) + ((cin ^ ((r >> 1) & 3)) * 8);      \
      __builtin_amdgcn_global_load_lds((const __attribute__((address_space(1))) void*)gv,\
          (__attribute__((address_space(3))) void*)(&Vs[buf][0] + ci * 8), 16, 0, 0);    \
    }                                                                                    \
  }

  // Q fragments: B-operand, lane: col=q=ql, k-slice (d) = kc*16 + hi*8
  bf16x8 qf[8];
#pragma unroll
  for (int kc = 0; kc < 8; ++kc)
    qf[kc] = *(const bf16x8*)(Q + (size_t)(q0 + ql) * HD + kc * 16 + hi * 8);

  // mask bias table + first KV stage
  for (int i = t; i < 2048; i += 256) biasLds[i] = mk[i] ? 0.f : NEG;
  STAGE_KV(0, 0);
  __syncthreads();
  if (t < 64) {
    int ok = 1;
    for (int j = 0; j < 32; ++j) ok &= (biasLds[t * 32 + j] == 0.f) ? 1 : 0;
    flagsLds[t] = ok;
  }
  __syncthreads();

  f32x16 acc[4] = {};
  float m_ = NEG, lp = 0.f;
  short* pl = &P[w][0];
  int cur = 0;

  for (int it = 0; it < 64; ++it) {
    int kv0 = it * 32;
    if (it + 1 < 64) STAGE_KV(cur ^ 1, kv0 + 32);

    const short* ks = &Ks[cur][0];
    const short* vs = &Vs[cur][0];

    // QK^T: sv[col=q][row=k_local]
    f32x16 sv = {};
    __builtin_amdgcn_s_setprio(1);
#pragma unroll
    for (int kc = 0; kc < 8; ++kc) {
      int chunk = (kc * 2 + hi) ^ (ql & 7);
      bf16x8 kf = *(const bf16x8*)(ks + ql * 128 + chunk * 8);
      sv = __builtin_amdgcn_mfma_f32_32x32x16_bf16(kf, qf[kc], sv, 0, 0, 0);
    }
    __builtin_amdgcn_s_setprio(0);

    // k_local(r) = (r&3) + 8*(r>>2) + 4*hi
    float p[16];
    int fl = flagsLds[it];
    if (fl) {
#pragma unroll
      for (int r = 0; r < 16; ++r) p[r] = sv[r];
    } else {
#pragma unroll
      for (int g2 = 0; g2 < 4; ++g2) {
        f32x4 bb = *(const f32x4*)(biasLds + kv0 + g2 * 8 + hi * 4);
#pragma unroll
        for (int j = 0; j < 4; ++j) p[g2 * 4 + j] = sv[g2 * 4 + j] + bb[j];
      }
    }

    // row max: 15 in-lane + 1 cross-half shuffle
    float a0 = fmaxf(fmaxf(p[0], p[1]), fmaxf(p[2], p[3]));
    float a1 = fmaxf(fmaxf(p[4], p[5]), fmaxf(p[6], p[7]));
    float a2 = fmaxf(fmaxf(p[8], p[9]), fmaxf(p[10], p[11]));
    float a3 = fmaxf(fmaxf(p[12], p[13]), fmaxf(p[14], p[15]));
    float rmx = fmaxf(fmaxf(a0, a1), fmaxf(a2, a3));
    rmx = fmaxf(rmx, __shfl_xor(rmx, 32));

    if (__any(rmx > m_ + 12.f)) {
      float mn = fmaxf(m_, rmx);
      float al = exp2f(m_ - mn);
      m_ = mn; lp *= al;
#pragma unroll
      for (int dt = 0; dt < 4; ++dt)
#pragma unroll
        for (int r = 0; r < 16; ++r) acc[dt][r] *= al;
    }

    float e[16];
#pragma unroll
    for (int r = 0; r < 16; ++r) e[r] = exp2f(p[r] - m_);
    float s0 = ((e[0] + e[1]) + (e[2] + e[3])) + ((e[4] + e[5]) + (e[6] + e[7]));
    float s1 = ((e[8] + e[9]) + (e[10] + e[11])) + ((e[12] + e[13]) + (e[14] + e[15]));
    lp += s0 + s1;

    // P^T pack: lane (q=ql) writes k = 8*g2 + 4*hi + {0..3} as two dwords (b64)
#pragma unroll
    for (int g2 = 0; g2 < 4; ++g2) {
      int2 pk;
      pk.x = (int)cvt_pk_bf16(e[4 * g2 + 0], e[4 * g2 + 1]);
      pk.y = (int)cvt_pk_bf16(e[4 * g2 + 2], e[4 * g2 + 3]);
      *(int2*)(pl + ql * 40 + g2 * 8 + hi * 4) = pk;
    }

    // PV: acc[dt][row=d_local] += Vt-frag x P^T-frag  (same-wave LDS, in-order)
    bf16x8 pf[2];
#pragma unroll
    for (int kt = 0; kt < 2; ++kt)
      pf[kt] = *(const bf16x8*)(pl + ql * 40 + (kt * 2 + hi) * 8);

    __builtin_amdgcn_s_setprio(1);
#pragma unroll
    for (int dt = 0; dt < 4; ++dt) {
      int d = dt * 32 + ql;
#pragma unroll
      for (int kt = 0; kt < 2; ++kt) {
        int chunk = (kt * 2 + hi) ^ ((d >> 1) & 3);
        bf16x8 vf = *(const bf16x8*)(vs + d * 32 + chunk * 8);
        acc[dt] = __builtin_amdgcn_mfma_f32_32x32x16_bf16(vf, pf[kt], acc[dt], 0, 0, 0);
      }
    }
    __builtin_amdgcn_s_setprio(0);

    __syncthreads();  // drains prefetch vmcnt + buffer swap
    cur ^= 1;
  }

  // final l: combine the two k-halves, then normalize + write
  lp += __shfl_xor(lp, 32);
  float inv = 1.f / lp;
  size_t orow = (size_t)(b * 2048 + q0 + ql) * 2048 + h * 128;
#pragma unroll
  for (int dt = 0; dt < 4; ++dt)
#pragma unroll
    for (int g2 = 0; g2 < 4; ++g2) {
      f32x4 v;
      v[0] = acc[dt][g2 * 4 + 0] * inv;
      v[1] = acc[dt][g2 * 4 + 1] * inv;
      v[2] = acc[dt][g2 * 4 + 2] * inv;
      v[3] = acc[dt][g2 * 4 + 3] * inv;
      int d = dt * 32 + g2 * 8 + hi * 4;
      *(f32x4*)(out + orow + d) = v;
    }
#undef STAGE_KV
}

// ---------------- launch ----------------

extern "C" void kernel_launch(void* const* d_in, const int* in_sizes, int n_in,
                              void* d_out, int out_size, void* d_ws, size_t ws_size,
                              hipStream_t stream) {
  const float* x = (const float*)d_in[0];
  const float* W = (const float*)d_in[1];
  const float* bias = (const float*)d_in[2];
  const void* mask = d_in[3];
  float* out = (float*)d_out;

  char* ws = (char*)d_ws;
  short* xb = (short*)(ws);
  short* wt = (short*)(ws + 16777216);
  short* qws = (short*)(ws + 41943040);
  short* kws = (short*)(ws + 58720256);
  short* vtws = (short*)(ws + 75497472);
  unsigned char* maskb = (unsigned char*)(ws + 92274688);

  convert_x_kernel<<<dim3(2048), dim3(256), 0, stream>>>(x, xb, 2 * 2048 * 2048);
  transpose_w_kernel<<<dim3(192, 64), dim3(32, 8), 0, stream>>>(W, wt);
  mask_norm_kernel<<<dim3(1), dim3(256), 0, stream>>>((const unsigned*)mask, maskb, 2 * 2048);
  qkv_gemm_kernel<<<dim3(1536), dim3(256), 0, stream>>>(xb, wt, bias, qws, kws, vtws);
  attn_kernel<<<dim3(512), dim3(256), 0, stream>>>(qws, kws, vtws, maskb, out);
}

// Round 5
// 350.004 us; speedup vs baseline: 2.0680x; 1.0670x over previous
//
#include <hip/hip_runtime.h>
#include <hip/hip_bf16.h>
#include <math.h>

typedef __attribute__((ext_vector_type(8))) short bf16x8;
typedef __attribute__((ext_vector_type(4))) float f32x4;
typedef __attribute__((ext_vector_type(16))) float f32x16;
typedef __attribute__((ext_vector_type(4))) short short4v;
typedef __attribute__((ext_vector_type(4))) int int4v;

__device__ __forceinline__ short f2bf(float f) {
  union { float f; unsigned u; } v; v.f = f;
  unsigned r = v.u + 0x7fffu + ((v.u >> 16) & 1u);
  return (short)(r >> 16);
}

__device__ __forceinline__ unsigned cvt_pk_bf16(float lo, float hi) {
  unsigned r;
  asm volatile("v_cvt_pk_bf16_f32 %0, %1, %2" : "=v"(r) : "v"(lo), "v"(hi));
  return r;
}

// ---------------- conversion kernels ----------------

__global__ void convert_x_kernel(const float* __restrict__ x, short* __restrict__ xb, int n) {
  int i = (blockIdx.x * blockDim.x + threadIdx.x) * 4;
  int stride = gridDim.x * blockDim.x * 4;
  for (; i < n; i += stride) {
    float4 v = *(const float4*)(x + i);
    short4v o;
    o.x = f2bf(v.x); o.y = f2bf(v.y); o.z = f2bf(v.z); o.w = f2bf(v.w);
    *(short4v*)(xb + i) = o;
  }
}

// W [2048][6144] f32 -> Wt [6144][2048] bf16
__global__ void transpose_w_kernel(const float* __restrict__ W, short* __restrict__ Wt) {
  __shared__ short tile[32][33];
  int n0 = blockIdx.x * 32, k0 = blockIdx.y * 32;
  int tx = threadIdx.x, ty = threadIdx.y; // (32, 8)
#pragma unroll
  for (int u = 0; u < 4; ++u) {
    int k = k0 + ty + u * 8;
    tile[ty + u * 8][tx] = f2bf(W[(size_t)k * 6144 + n0 + tx]);
  }
  __syncthreads();
#pragma unroll
  for (int u = 0; u < 4; ++u) {
    int n = n0 + ty + u * 8;
    Wt[(size_t)n * 2048 + k0 + tx] = tile[tx][ty + u * 8];
  }
}

// Normalize mask to u8 0/1, detecting storage layout (bool-bytes / int32 / f32).
__global__ void mask_norm_kernel(const unsigned* __restrict__ m, unsigned char* __restrict__ out, int n) {
  __shared__ int flagA, flagB;
  if (threadIdx.x == 0) { flagA = 0; flagB = 0; }
  __syncthreads();
  int a = 0, b = 0;
  for (int i = threadIdx.x; i < n / 4; i += blockDim.x) {
    unsigned wv = m[i];
    if (wv > 1u) a = 1;
    if (wv != 0u && wv != 0x3f800000u) b = 1;
  }
  if (a) atomicOr(&flagA, 1);
  if (b) atomicOr(&flagB, 1);
  __syncthreads();
  int A = flagA, B = flagB;
  for (int i = threadIdx.x; i < n; i += blockDim.x) {
    unsigned char r;
    if (!A) r = (m[i] != 0u) ? 1 : 0;
    else if (!B) r = (((const float*)m)[i] != 0.f) ? 1 : 0;
    else r = (((const unsigned char*)m)[i] != 0) ? 1 : 0;
    out[i] = r;
  }
}

// ---------------- QKV GEMM: 256^2 tile, 4-phase/K-tile, counted vmcnt ----------
// A: x bf16 [4096][2048]; Bt: Wt bf16 [6144][2048].
// 8 waves (2M x 4N), interleaved frag map: M-frag gm = wr + 2*mi, N-frag gn = wc + 4*nj
// LDS: 2 buf x { A: 2 halves [128][64], B: 2 halves [128][64] } = 128 KiB, swizzle chunk^=(row&7)

__global__ __launch_bounds__(512, 2) void qkv_gemm_kernel(
    const short* __restrict__ A, const short* __restrict__ Bt, const float* __restrict__ bias,
    short* __restrict__ qws, short* __restrict__ kws, short* __restrict__ vtws) {
  __shared__ __align__(16) char smem[131072];

  int lid = blockIdx.x;                 // 384 blocks
  int swz = (lid & 7) * 48 + (lid >> 3);
  int tm = swz / 24, tn = swz % 24;
  int m0 = tm * 256, n0 = tn * 256;
  int t = threadIdx.x, lane = t & 63, w = t >> 6;
  int wr = w >> 2, wc = w & 3;
  int g = lane >> 4, c = lane & 15;

#define AHP(P, hm) (smem + (P) * 65536 + (hm) * 16384)
#define BHP(P, hn) (smem + (P) * 65536 + 32768 + (hn) * 16384)

#define STAGE_HALF(ldsb, gbase)                                                            \
  { _Pragma("unroll")                                                                      \
    for (int rr = 0; rr < 2; ++rr) {                                                       \
      int ci = rr * 512 + t;                                                               \
      int row_ = ci >> 3, ch_ = ci & 7;                                                    \
      const short* gp_ = (gbase) + (size_t)row_ * 2048 + ((ch_ ^ (row_ & 7)) * 8);         \
      __builtin_amdgcn_global_load_lds((const __attribute__((address_space(1))) void*)gp_, \
          (__attribute__((address_space(3))) void*)((ldsb) + ci * 16), 16, 0, 0);          \
    } }

  // per-phase 12/4/8/4 ds_read_b128, conflict-free via chunk^(row&7)
#define LD_A(half)                                                                          \
  { const char* ab_ = AHP(P, half);                                                         \
    _Pragma("unroll")                                                                       \
    for (int mi = 0; mi < 4; ++mi) {                                                        \
      int row_ = wr * 16 + c + mi * 32;                                                     \
      _Pragma("unroll")                                                                     \
      for (int ks = 0; ks < 2; ++ks)                                                        \
        af[mi][ks] = *(const bf16x8*)(ab_ + row_ * 128 + (((ks * 4 + g) ^ (row_ & 7)) * 16)); \
    } }
#define LD_B(half)                                                                          \
  { const char* bb_ = BHP(P, half);                                                         \
    _Pragma("unroll")                                                                       \
    for (int nj = 0; nj < 2; ++nj) {                                                        \
      int row_ = wc * 16 + c + nj * 64;                                                     \
      _Pragma("unroll")                                                                     \
      for (int ks = 0; ks < 2; ++ks)                                                        \
        bfr[nj][ks] = *(const bf16x8*)(bb_ + row_ * 128 + (((ks * 4 + g) ^ (row_ & 7)) * 16)); \
    } }
#define MFMA16(MI0, NJ0)                                                                    \
  __builtin_amdgcn_s_setprio(1);                                                            \
  _Pragma("unroll")                                                                         \
  for (int mi = 0; mi < 4; ++mi)                                                            \
    _Pragma("unroll")                                                                       \
    for (int nj = 0; nj < 2; ++nj)                                                          \
      _Pragma("unroll")                                                                     \
      for (int ks = 0; ks < 2; ++ks)                                                        \
        acc[(MI0) + mi][(NJ0) + nj] =                                                       \
            __builtin_amdgcn_mfma_f32_16x16x32_bf16(af[mi][ks], bfr[nj][ks],                \
                                                    acc[(MI0) + mi][(NJ0) + nj], 0, 0, 0);  \
  __builtin_amdgcn_s_setprio(0);

  // prologue: tile 0, issue order A0,B0,B1,A1 (matches steady-state retire order)
  STAGE_HALF(AHP(0, 0), A + (size_t)m0 * 2048);
  STAGE_HALF(BHP(0, 0), Bt + (size_t)n0 * 2048);
  STAGE_HALF(BHP(0, 1), Bt + (size_t)(n0 + 128) * 2048);
  STAGE_HALF(AHP(0, 1), A + (size_t)(m0 + 128) * 2048);
  asm volatile("s_waitcnt vmcnt(4)" ::: "memory");
  __builtin_amdgcn_s_barrier();

  f32x4 acc[8][4] = {};

  for (int tk = 0; tk < 32; ++tk) {
    int P = tk & 1, Pn = P ^ 1;
    bool pf = (tk + 1 < 32);
    int k1 = (tk + 1) * 64;
    bf16x8 af[4][2], bfr[2][2];

    // ---- phase 1: quadrant (qm=0, qn=0) ----
    LD_A(0); LD_B(0);
    if (pf) STAGE_HALF(AHP(Pn, 0), A + (size_t)m0 * 2048 + k1);
    MFMA16(0, 0);
    if (pf) { asm volatile("s_waitcnt vmcnt(4)" ::: "memory"); }
    else    { asm volatile("s_waitcnt vmcnt(2)" ::: "memory"); }
    __builtin_amdgcn_s_barrier();

    // ---- phase 2: (0,1), reuse af ----
    LD_B(1);
    if (pf) STAGE_HALF(BHP(Pn, 0), Bt + (size_t)n0 * 2048 + k1);
    MFMA16(0, 2);
    if (pf) { asm volatile("s_waitcnt vmcnt(4)" ::: "memory"); }
    else    { asm volatile("s_waitcnt vmcnt(0)" ::: "memory"); }
    __builtin_amdgcn_s_barrier();

    // ---- phase 3: (1,1), reuse bfr ----
    LD_A(1);
    if (pf) STAGE_HALF(BHP(Pn, 1), Bt + (size_t)(n0 + 128) * 2048 + k1);
    MFMA16(4, 2);
    __builtin_amdgcn_s_barrier();

    // ---- phase 4: (1,0), reuse af ----
    LD_B(0);
    if (pf) STAGE_HALF(AHP(Pn, 1), A + (size_t)(m0 + 128) * 2048 + k1);
    MFMA16(4, 0);
    if (pf) { asm volatile("s_waitcnt vmcnt(4)" ::: "memory"); }
    __builtin_amdgcn_s_barrier();
  }

  // ---------------- epilogue ----------------
  int sec = n0 >> 11;
  int b = m0 >> 11;
  int s0 = m0 & 2047;
  int nsec = n0 & 2047;

  if (sec < 2) {
    short* base = (sec == 0 ? qws : kws);
    const float scq = (sec == 0) ? (0.08838834764831845f * 1.4426950408889634f) : 1.0f;
#pragma unroll
    for (int nj = 0; nj < 4; ++nj) {
      int colsec = nsec + wc * 16 + nj * 64;      // strip base (mult of 16)
      float bv = bias[n0 + wc * 16 + nj * 64 + c];
      int h = colsec >> 7;
      int d = (colsec & 127) + c;
      short* dst = base + ((size_t)(b * 16 + h)) * (2048 * 128) + d;
#pragma unroll
      for (int mi = 0; mi < 8; ++mi) {
        int srow = s0 + (wr + 2 * mi) * 16 + g * 4;
#pragma unroll
        for (int r = 0; r < 4; ++r)
          dst[(size_t)(srow + r) * 128] = f2bf((acc[mi][nj][r] + bv) * scq);
      }
    }
  } else {
    // V: per-wave private LDS transpose (16 KB region), then b128 stores along s
    __builtin_amdgcn_s_barrier();   // all waves done reading main-loop LDS
    char* wreg = smem + w * 16384;
#pragma unroll
    for (int nj = 0; nj < 4; ++nj) {
      float bv = bias[n0 + wc * 16 + nj * 64 + c];
      int d = nj * 16 + c;
#pragma unroll
      for (int mi = 0; mi < 8; ++mi)
#pragma unroll
        for (int r = 0; r < 4; ++r) {
          int sloc = mi * 16 + g * 4 + r;
          *(short*)(wreg + d * 256 + (((sloc >> 3) ^ (d & 15)) * 16) + (sloc & 7) * 2) =
              f2bf(acc[mi][nj][r] + bv);
        }
    }
    // read own region (in-wave ordering handled by compiler waits)
#pragma unroll
    for (int q = 0; q < 16; ++q) {
      int d = q * 4 + g;
      bf16x8 v = *(const bf16x8*)(wreg + d * 256 + ((c ^ (d & 15)) * 16));
      int colsec = nsec + wc * 16 + (d >> 4) * 64 + (d & 15);
      int h = colsec >> 7, dloc = colsec & 127;
      int srow = s0 + wr * 16 + (c >> 1) * 32 + (c & 1) * 8;
      *(bf16x8*)(vtws + ((size_t)(b * 16 + h)) * (128 * 2048) + (size_t)dloc * 2048 + srow) = v;
    }
  }
#undef AHP
#undef BHP
#undef STAGE_HALF
#undef LD_A
#undef LD_B
#undef MFMA16
}

// ---------------- flash attention (swapped-operand 32x32x16) ----------------
// Q(prescaled by hd^-0.5*log2e),K: [B,H,S,128] bf16; Vt: [B,H,128,S] bf16; out f32.

__global__ __launch_bounds__(256, 2) void attn_kernel(
    const short* __restrict__ qws, const short* __restrict__ kws, const short* __restrict__ vtws,
    const unsigned char* __restrict__ maskb, float* __restrict__ out) {
  __shared__ short Ks[2][32 * 128];   // [kv 32][d 128], chunk ^= (row&7)
  __shared__ short Vs[2][128 * 32];   // [d 128][kv 32], chunk ^= ((row>>1)&3)
  __shared__ short P[4][32 * 40];     // per-wave [q 32][kv 32 + pad]
  __shared__ float biasLds[2048];
  __shared__ int flagsLds[64];

  const int S = 2048, HD = 128;
  int lid = blockIdx.x;                    // 512 blocks
  int swz = (lid & 7) * 64 + (lid >> 3);
  int bh = swz >> 4, qblk = swz & 15;
  int b = bh >> 4, h = bh & 15;
  int t = threadIdx.x, lane = t & 63, w = t >> 6;
  int ql = lane & 31, hi = lane >> 5;
  int q0 = qblk * 128 + w * 32;
  const short* Q = qws + (size_t)bh * S * HD;
  const short* Kp = kws + (size_t)bh * S * HD;
  const short* Vt = vtws + (size_t)bh * HD * S;
  const unsigned char* mk = maskb + b * S;
  const float NEG = -3.4028235e38f;

#define STAGE_KV(buf, kv0_)                                                              \
  {                                                                                      \
    _Pragma("unroll")                                                                    \
    for (int rr = 0; rr < 2; ++rr) {                                                     \
      int ci = rr * 256 + t;                                                             \
      int r = ci >> 4, cin = ci & 15;                                                    \
      const short* gk = Kp + (size_t)((kv0_) + r) * HD + ((cin ^ (r & 7)) * 8);          \
      __builtin_amdgcn_global_load_lds((const __attribute__((address_space(1))) void*)gk,\
          (__attribute__((address_space(3))) void*)(&Ks[buf][0] + ci * 8), 16, 0, 0);    \
    }                                                                                    \
    _Pragma("unroll")                                                                    \
    for (int rr = 0; rr < 2; ++rr) {                                                     \
      int ci = rr * 256 + t;                                                             \
      int r = ci >> 2, cin = ci & 3;                                                     \
      const short* gv = Vt + (size_t)r * S + (kv0_) + ((cin ^ ((r >> 1) & 3)) * 8);      \
      __builtin_amdgcn_global_load_lds((const __attribute__((address_space(1))) void*)gv,\
          (__attribute__((address_space(3))) void*)(&Vs[buf][0] + ci * 8), 16, 0, 0);    \
    }                                                                                    \
  }

  // Q fragments: B-operand, lane: col=q=ql, k-slice (d) = kc*16 + hi*8
  bf16x8 qf[8];
#pragma unroll
  for (int kc = 0; kc < 8; ++kc)
    qf[kc] = *(const bf16x8*)(Q + (size_t)(q0 + ql) * HD + kc * 16 + hi * 8);

  // mask bias table + first KV stage
  for (int i = t; i < 2048; i += 256) biasLds[i] = mk[i] ? 0.f : NEG;
  STAGE_KV(0, 0);
  __syncthreads();
  if (t < 64) {
    int ok = 1;
    for (int j = 0; j < 32; ++j) ok &= (biasLds[t * 32 + j] == 0.f) ? 1 : 0;
    flagsLds[t] = ok;
  }
  __syncthreads();

  f32x16 acc[4] = {};
  float m_ = NEG, lp = 0.f;
  short* pl = &P[w][0];
  int cur = 0;

  for (int it = 0; it < 64; ++it) {
    int kv0 = it * 32;
    if (it + 1 < 64) STAGE_KV(cur ^ 1, kv0 + 32);

    const short* ks = &Ks[cur][0];
    const short* vs = &Vs[cur][0];

    // QK^T: sv[col=q][row=k_local]
    f32x16 sv = {};
    __builtin_amdgcn_s_setprio(1);
#pragma unroll
    for (int kc = 0; kc < 8; ++kc) {
      int chunk = (kc * 2 + hi) ^ (ql & 7);
      bf16x8 kf = *(const bf16x8*)(ks + ql * 128 + chunk * 8);
      sv = __builtin_amdgcn_mfma_f32_32x32x16_bf16(kf, qf[kc], sv, 0, 0, 0);
    }
    __builtin_amdgcn_s_setprio(0);

    // k_local(r) = (r&3) + 8*(r>>2) + 4*hi
    float p[16];
    int fl = flagsLds[it];
    if (fl) {
#pragma unroll
      for (int r = 0; r < 16; ++r) p[r] = sv[r];
    } else {
#pragma unroll
      for (int g2 = 0; g2 < 4; ++g2) {
        f32x4 bb = *(const f32x4*)(biasLds + kv0 + g2 * 8 + hi * 4);
#pragma unroll
        for (int j = 0; j < 4; ++j) p[g2 * 4 + j] = sv[g2 * 4 + j] + bb[j];
      }
    }

    // row max: 15 in-lane + 1 cross-half shuffle
    float a0 = fmaxf(fmaxf(p[0], p[1]), fmaxf(p[2], p[3]));
    float a1 = fmaxf(fmaxf(p[4], p[5]), fmaxf(p[6], p[7]));
    float a2 = fmaxf(fmaxf(p[8], p[9]), fmaxf(p[10], p[11]));
    float a3 = fmaxf(fmaxf(p[12], p[13]), fmaxf(p[14], p[15]));
    float rmx = fmaxf(fmaxf(a0, a1), fmaxf(a2, a3));
    rmx = fmaxf(rmx, __shfl_xor(rmx, 32));

    if (__any(rmx > m_ + 12.f)) {
      float mn = fmaxf(m_, rmx);
      float al = exp2f(m_ - mn);
      m_ = mn; lp *= al;
#pragma unroll
      for (int dt = 0; dt < 4; ++dt)
#pragma unroll
        for (int r = 0; r < 16; ++r) acc[dt][r] *= al;
    }

    float e[16];
#pragma unroll
    for (int r = 0; r < 16; ++r) e[r] = exp2f(p[r] - m_);
    float s0 = ((e[0] + e[1]) + (e[2] + e[3])) + ((e[4] + e[5]) + (e[6] + e[7]));
    float s1 = ((e[8] + e[9]) + (e[10] + e[11])) + ((e[12] + e[13]) + (e[14] + e[15]));
    lp += s0 + s1;

    // P^T pack: lane (q=ql) writes k = 8*g2 + 4*hi + {0..3} as one b64
#pragma unroll
    for (int g2 = 0; g2 < 4; ++g2) {
      int2 pk;
      pk.x = (int)cvt_pk_bf16(e[4 * g2 + 0], e[4 * g2 + 1]);
      pk.y = (int)cvt_pk_bf16(e[4 * g2 + 2], e[4 * g2 + 3]);
      *(int2*)(pl + ql * 40 + g2 * 8 + hi * 4) = pk;
    }

    // PV: acc[dt][row=d_local] += Vt-frag x P^T-frag  (same-wave LDS, in-order)
    bf16x8 pf[2];
#pragma unroll
    for (int kt = 0; kt < 2; ++kt)
      pf[kt] = *(const bf16x8*)(pl + ql * 40 + (kt * 2 + hi) * 8);

    __builtin_amdgcn_s_setprio(1);
#pragma unroll
    for (int dt = 0; dt < 4; ++dt) {
      int d = dt * 32 + ql;
#pragma unroll
      for (int kt = 0; kt < 2; ++kt) {
        int chunk = (kt * 2 + hi) ^ ((d >> 1) & 3);
        bf16x8 vf = *(const bf16x8*)(vs + d * 32 + chunk * 8);
        acc[dt] = __builtin_amdgcn_mfma_f32_32x32x16_bf16(vf, pf[kt], acc[dt], 0, 0, 0);
      }
    }
    __builtin_amdgcn_s_setprio(0);

    __syncthreads();  // drains prefetch vmcnt + buffer swap
    cur ^= 1;
  }

  // final l: combine the two k-halves, then normalize + write
  lp += __shfl_xor(lp, 32);
  float inv = 1.f / lp;
  size_t orow = (size_t)(b * 2048 + q0 + ql) * 2048 + h * 128;
#pragma unroll
  for (int dt = 0; dt < 4; ++dt)
#pragma unroll
    for (int g2 = 0; g2 < 4; ++g2) {
      f32x4 v;
      v[0] = acc[dt][g2 * 4 + 0] * inv;
      v[1] = acc[dt][g2 * 4 + 1] * inv;
      v[2] = acc[dt][g2 * 4 + 2] * inv;
      v[3] = acc[dt][g2 * 4 + 3] * inv;
      int d = dt * 32 + g2 * 8 + hi * 4;
      *(f32x4*)(out + orow + d) = v;
    }
#undef STAGE_KV
}

// ---------------- launch ----------------

extern "C" void kernel_launch(void* const* d_in, const int* in_sizes, int n_in,
                              void* d_out, int out_size, void* d_ws, size_t ws_size,
                              hipStream_t stream) {
  const float* x = (const float*)d_in[0];
  const float* W = (const float*)d_in[1];
  const float* bias = (const float*)d_in[2];
  const void* mask = d_in[3];
  float* out = (float*)d_out;

  char* ws = (char*)d_ws;
  short* xb = (short*)(ws);
  short* wt = (short*)(ws + 16777216);
  short* qws = (short*)(ws + 41943040);
  short* kws = (short*)(ws + 58720256);
  short* vtws = (short*)(ws + 75497472);
  unsigned char* maskb = (unsigned char*)(ws + 92274688);

  convert_x_kernel<<<dim3(2048), dim3(256), 0, stream>>>(x, xb, 2 * 2048 * 2048);
  transpose_w_kernel<<<dim3(192, 64), dim3(32, 8), 0, stream>>>(W, wt);
  mask_norm_kernel<<<dim3(1), dim3(256), 0, stream>>>((const unsigned*)mask, maskb, 2 * 2048);
  qkv_gemm_kernel<<<dim3(384), dim3(512), 0, stream>>>(xb, wt, bias, qws, kws, vtws);
  attn_kernel<<<dim3(512), dim3(256), 0, stream>>>(qws, kws, vtws, maskb, out);
}

// Round 6
// 334.933 us; speedup vs baseline: 2.1611x; 1.0450x over previous
//
#include <hip/hip_runtime.h>
#include <hip/hip_bf16.h>
#include <math.h>

typedef __attribute__((ext_vector_type(8))) short bf16x8;
typedef __attribute__((ext_vector_type(4))) float f32x4;
typedef __attribute__((ext_vector_type(16))) float f32x16;
typedef __attribute__((ext_vector_type(4))) short short4v;
typedef __attribute__((ext_vector_type(4))) int int4v;
typedef __attribute__((ext_vector_type(4))) unsigned uint4v;

__device__ __forceinline__ short f2bf(float f) {
  union { float f; unsigned u; } v; v.f = f;
  unsigned r = v.u + 0x7fffu + ((v.u >> 16) & 1u);
  return (short)(r >> 16);
}

__device__ __forceinline__ unsigned cvt_pk_bf16(float lo, float hi) {
  unsigned r;
  asm volatile("v_cvt_pk_bf16_f32 %0, %1, %2" : "=v"(r) : "v"(lo), "v"(hi));
  return r;
}

// ---------------- conversion kernels ----------------

__global__ void convert_x_kernel(const float* __restrict__ x, short* __restrict__ xb, int n) {
  int i = (blockIdx.x * blockDim.x + threadIdx.x) * 4;
  int stride = gridDim.x * blockDim.x * 4;
  for (; i < n; i += stride) {
    float4 v = *(const float4*)(x + i);
    short4v o;
    o.x = f2bf(v.x); o.y = f2bf(v.y); o.z = f2bf(v.z); o.w = f2bf(v.w);
    *(short4v*)(xb + i) = o;
  }
}

// W [2048][6144] f32 -> Wt [6144][2048] bf16
__global__ void transpose_w_kernel(const float* __restrict__ W, short* __restrict__ Wt) {
  __shared__ short tile[32][33];
  int n0 = blockIdx.x * 32, k0 = blockIdx.y * 32;
  int tx = threadIdx.x, ty = threadIdx.y; // (32, 8)
#pragma unroll
  for (int u = 0; u < 4; ++u) {
    int k = k0 + ty + u * 8;
    tile[ty + u * 8][tx] = f2bf(W[(size_t)k * 6144 + n0 + tx]);
  }
  __syncthreads();
#pragma unroll
  for (int u = 0; u < 4; ++u) {
    int n = n0 + ty + u * 8;
    Wt[(size_t)n * 2048 + k0 + tx] = tile[tx][ty + u * 8];
  }
}

// Normalize mask to u8 0/1, detecting storage layout (bool-bytes / int32 / f32).
__global__ void mask_norm_kernel(const unsigned* __restrict__ m, unsigned char* __restrict__ out, int n) {
  __shared__ int flagA, flagB;
  if (threadIdx.x == 0) { flagA = 0; flagB = 0; }
  __syncthreads();
  int a = 0, b = 0;
  for (int i = threadIdx.x; i < n / 4; i += blockDim.x) {
    unsigned wv = m[i];
    if (wv > 1u) a = 1;
    if (wv != 0u && wv != 0x3f800000u) b = 1;
  }
  if (a) atomicOr(&flagA, 1);
  if (b) atomicOr(&flagB, 1);
  __syncthreads();
  int A = flagA, B = flagB;
  for (int i = threadIdx.x; i < n; i += blockDim.x) {
    unsigned char r;
    if (!A) r = (m[i] != 0u) ? 1 : 0;
    else if (!B) r = (((const float*)m)[i] != 0.f) ? 1 : 0;
    else r = (((const unsigned char*)m)[i] != 0) ? 1 : 0;
    out[i] = r;
  }
}

// ---------------- QKV GEMM: 256^2 tile, 4-phase/K-tile, counted vmcnt ----------

__global__ __launch_bounds__(512, 2) void qkv_gemm_kernel(
    const short* __restrict__ A, const short* __restrict__ Bt, const float* __restrict__ bias,
    short* __restrict__ qws, short* __restrict__ kws, short* __restrict__ vtws) {
  __shared__ __align__(16) char smem[131072];

  int lid = blockIdx.x;                 // 384 blocks
  int swz = (lid & 7) * 48 + (lid >> 3);
  int tm = swz / 24, tn = swz % 24;
  int m0 = tm * 256, n0 = tn * 256;
  int t = threadIdx.x, lane = t & 63, w = t >> 6;
  int wr = w >> 2, wc = w & 3;
  int g = lane >> 4, c = lane & 15;

#define AHP(P, hm) (smem + (P) * 65536 + (hm) * 16384)
#define BHP(P, hn) (smem + (P) * 65536 + 32768 + (hn) * 16384)

#define STAGE_HALF(ldsb, gbase)                                                            \
  { _Pragma("unroll")                                                                      \
    for (int rr = 0; rr < 2; ++rr) {                                                       \
      int ci = rr * 512 + t;                                                               \
      int row_ = ci >> 3, ch_ = ci & 7;                                                    \
      const short* gp_ = (gbase) + (size_t)row_ * 2048 + ((ch_ ^ (row_ & 7)) * 8);         \
      __builtin_amdgcn_global_load_lds((const __attribute__((address_space(1))) void*)gp_, \
          (__attribute__((address_space(3))) void*)((ldsb) + ci * 16), 16, 0, 0);          \
    } }

#define LD_A(half)                                                                          \
  { const char* ab_ = AHP(P, half);                                                         \
    _Pragma("unroll")                                                                       \
    for (int mi = 0; mi < 4; ++mi) {                                                        \
      int row_ = wr * 16 + c + mi * 32;                                                     \
      _Pragma("unroll")                                                                     \
      for (int ks = 0; ks < 2; ++ks)                                                        \
        af[mi][ks] = *(const bf16x8*)(ab_ + row_ * 128 + (((ks * 4 + g) ^ (row_ & 7)) * 16)); \
    } }
#define LD_B(half)                                                                          \
  { const char* bb_ = BHP(P, half);                                                         \
    _Pragma("unroll")                                                                       \
    for (int nj = 0; nj < 2; ++nj) {                                                        \
      int row_ = wc * 16 + c + nj * 64;                                                     \
      _Pragma("unroll")                                                                     \
      for (int ks = 0; ks < 2; ++ks)                                                        \
        bfr[nj][ks] = *(const bf16x8*)(bb_ + row_ * 128 + (((ks * 4 + g) ^ (row_ & 7)) * 16)); \
    } }
#define MFMA16(MI0, NJ0)                                                                    \
  __builtin_amdgcn_s_setprio(1);                                                            \
  _Pragma("unroll")                                                                         \
  for (int mi = 0; mi < 4; ++mi)                                                            \
    _Pragma("unroll")                                                                       \
    for (int nj = 0; nj < 2; ++nj)                                                          \
      _Pragma("unroll")                                                                     \
      for (int ks = 0; ks < 2; ++ks)                                                        \
        acc[(MI0) + mi][(NJ0) + nj] =                                                       \
            __builtin_amdgcn_mfma_f32_16x16x32_bf16(af[mi][ks], bfr[nj][ks],                \
                                                    acc[(MI0) + mi][(NJ0) + nj], 0, 0, 0);  \
  __builtin_amdgcn_s_setprio(0);

  STAGE_HALF(AHP(0, 0), A + (size_t)m0 * 2048);
  STAGE_HALF(BHP(0, 0), Bt + (size_t)n0 * 2048);
  STAGE_HALF(BHP(0, 1), Bt + (size_t)(n0 + 128) * 2048);
  STAGE_HALF(AHP(0, 1), A + (size_t)(m0 + 128) * 2048);
  asm volatile("s_waitcnt vmcnt(4)" ::: "memory");
  __builtin_amdgcn_s_barrier();

  f32x4 acc[8][4] = {};

  for (int tk = 0; tk < 32; ++tk) {
    int P = tk & 1, Pn = P ^ 1;
    bool pf = (tk + 1 < 32);
    int k1 = (tk + 1) * 64;
    bf16x8 af[4][2], bfr[2][2];

    LD_A(0); LD_B(0);
    if (pf) STAGE_HALF(AHP(Pn, 0), A + (size_t)m0 * 2048 + k1);
    MFMA16(0, 0);
    if (pf) { asm volatile("s_waitcnt vmcnt(4)" ::: "memory"); }
    else    { asm volatile("s_waitcnt vmcnt(2)" ::: "memory"); }
    __builtin_amdgcn_s_barrier();

    LD_B(1);
    if (pf) STAGE_HALF(BHP(Pn, 0), Bt + (size_t)n0 * 2048 + k1);
    MFMA16(0, 2);
    if (pf) { asm volatile("s_waitcnt vmcnt(4)" ::: "memory"); }
    else    { asm volatile("s_waitcnt vmcnt(0)" ::: "memory"); }
    __builtin_amdgcn_s_barrier();

    LD_A(1);
    if (pf) STAGE_HALF(BHP(Pn, 1), Bt + (size_t)(n0 + 128) * 2048 + k1);
    MFMA16(4, 2);
    __builtin_amdgcn_s_barrier();

    LD_B(0);
    if (pf) STAGE_HALF(AHP(Pn, 1), A + (size_t)(m0 + 128) * 2048 + k1);
    MFMA16(4, 0);
    if (pf) { asm volatile("s_waitcnt vmcnt(4)" ::: "memory"); }
    __builtin_amdgcn_s_barrier();
  }

  // ---------------- epilogue ----------------
  int sec = n0 >> 11;
  int b = m0 >> 11;
  int s0 = m0 & 2047;
  int nsec = n0 & 2047;

  if (sec < 2) {
    short* base = (sec == 0 ? qws : kws);
    const float scq = (sec == 0) ? (0.08838834764831845f * 1.4426950408889634f) : 1.0f;
#pragma unroll
    for (int nj = 0; nj < 4; ++nj) {
      int colsec = nsec + wc * 16 + nj * 64;
      float bv = bias[n0 + wc * 16 + nj * 64 + c];
      int h = colsec >> 7;
      int d = (colsec & 127) + c;
      short* dst = base + ((size_t)(b * 16 + h)) * (2048 * 128) + d;
#pragma unroll
      for (int mi = 0; mi < 8; ++mi) {
        int srow = s0 + (wr + 2 * mi) * 16 + g * 4;
#pragma unroll
        for (int r = 0; r < 4; ++r)
          dst[(size_t)(srow + r) * 128] = f2bf((acc[mi][nj][r] + bv) * scq);
      }
    }
  } else {
    __builtin_amdgcn_s_barrier();
    char* wreg = smem + w * 16384;
#pragma unroll
    for (int nj = 0; nj < 4; ++nj) {
      float bv = bias[n0 + wc * 16 + nj * 64 + c];
      int d = nj * 16 + c;
#pragma unroll
      for (int mi = 0; mi < 8; ++mi)
#pragma unroll
        for (int r = 0; r < 4; ++r) {
          int sloc = mi * 16 + g * 4 + r;
          *(short*)(wreg + d * 256 + (((sloc >> 3) ^ (d & 15)) * 16) + (sloc & 7) * 2) =
              f2bf(acc[mi][nj][r] + bv);
        }
    }
#pragma unroll
    for (int q = 0; q < 16; ++q) {
      int d = q * 4 + g;
      bf16x8 v = *(const bf16x8*)(wreg + d * 256 + ((c ^ (d & 15)) * 16));
      int colsec = nsec + wc * 16 + (d >> 4) * 64 + (d & 15);
      int h = colsec >> 7, dloc = colsec & 127;
      int srow = s0 + wr * 16 + (c >> 1) * 32 + (c & 1) * 8;
      *(bf16x8*)(vtws + ((size_t)(b * 16 + h)) * (128 * 2048) + (size_t)dloc * 2048 + srow) = v;
    }
  }
#undef AHP
#undef BHP
#undef STAGE_HALF
#undef LD_A
#undef LD_B
#undef MFMA16
}

// ---------------- flash attention (swapped 32x32x16, reg-P, 1-tile pipeline) ----
// Q(prescaled by hd^-0.5*log2e),K: [B,H,S,128] bf16; Vt: [B,H,128,S] bf16; out f32.
// Per iter: QK(t) MFMA || PV(t-1) MFMA || prefetch(t+1) || V(t)->regs, then
// softmax(t) VALU overlaps the MFMA tail. P never touches LDS (cvt_pk + permlane32_swap).

__global__ __launch_bounds__(256, 2) void attn_kernel(
    const short* __restrict__ qws, const short* __restrict__ kws, const short* __restrict__ vtws,
    const unsigned char* __restrict__ maskb, float* __restrict__ out) {
  __shared__ short Ks[2][32 * 128];   // [kv 32][d 128], chunk ^= (row&7)
  __shared__ short Vs[2][128 * 32];   // [d 128][kv 32], chunk ^= ((row>>1)&3)
  __shared__ float biasLds[2048];
  __shared__ int flagsLds[64];

  const int S = 2048, HD = 128;
  int lid = blockIdx.x;                    // 512 blocks
  int swz = (lid & 7) * 64 + (lid >> 3);
  int bh = swz >> 4, qblk = swz & 15;
  int b = bh >> 4, h = bh & 15;
  int t = threadIdx.x, lane = t & 63, w = t >> 6;
  int ql = lane & 31, hi = lane >> 5;
  int q0 = qblk * 128 + w * 32;
  const short* Q = qws + (size_t)bh * S * HD;
  const short* Kp = kws + (size_t)bh * S * HD;
  const short* Vt = vtws + (size_t)bh * HD * S;
  const unsigned char* mk = maskb + b * S;
  const float NEG = -3.4028235e38f;

#define STAGE_KV(buf, kv0_)                                                              \
  {                                                                                      \
    _Pragma("unroll")                                                                    \
    for (int rr = 0; rr < 2; ++rr) {                                                     \
      int ci = rr * 256 + t;                                                             \
      int r = ci >> 4, cin = ci & 15;                                                    \
      const short* gk = Kp + (size_t)((kv0_) + r) * HD + ((cin ^ (r & 7)) * 8);          \
      __builtin_amdgcn_global_load_lds((const __attribute__((address_space(1))) void*)gk,\
          (__attribute__((address_space(3))) void*)(&Ks[buf][0] + ci * 8), 16, 0, 0);    \
    }                                                                                    \
    _Pragma("unroll")                                                                    \
    for (int rr = 0; rr < 2; ++rr) {                                                     \
      int ci = rr * 256 + t;                                                             \
      int r = ci >> 2, cin = ci & 3;                                                     \
      const short* gv = Vt + (size_t)r * S + (kv0_) + ((cin ^ ((r >> 1) & 3)) * 8);      \
      __builtin_amdgcn_global_load_lds((const __attribute__((address_space(1))) void*)gv,\
          (__attribute__((address_space(3))) void*)(&Vs[buf][0] + ci * 8), 16, 0, 0);    \
    }                                                                                    \
  }

#define QK_PHASE(CUR)                                                                    \
  { const short* ks = &Ks[CUR][0];                                                       \
    _Pragma("unroll") for (int r = 0; r < 16; ++r) sv[r] = 0.f;                          \
    __builtin_amdgcn_s_setprio(1);                                                       \
    _Pragma("unroll") for (int kc = 0; kc < 8; ++kc) {                                   \
      int chunk = (kc * 2 + hi) ^ (ql & 7);                                              \
      bf16x8 kf = *(const bf16x8*)(ks + ql * 128 + chunk * 8);                           \
      sv = __builtin_amdgcn_mfma_f32_32x32x16_bf16(kf, qf[kc], sv, 0, 0, 0);             \
    }                                                                                    \
    __builtin_amdgcn_s_setprio(0); }

#define PV_PHASE()                                                                       \
  { __builtin_amdgcn_s_setprio(1);                                                       \
    _Pragma("unroll") for (int dt = 0; dt < 4; ++dt)                                     \
      _Pragma("unroll") for (int kt = 0; kt < 2; ++kt)                                   \
        acc[dt] = __builtin_amdgcn_mfma_f32_32x32x16_bf16(vreg[dt * 2 + kt], pfv[kt],    \
                                                          acc[dt], 0, 0, 0);             \
    __builtin_amdgcn_s_setprio(0); }

#define LOADV(CUR)                                                                       \
  { const short* vs = &Vs[CUR][0];                                                       \
    _Pragma("unroll") for (int dt = 0; dt < 4; ++dt)                                     \
      _Pragma("unroll") for (int kt = 0; kt < 2; ++kt) {                                 \
        int d = dt * 32 + ql;                                                            \
        int chunk = (kt * 2 + hi) ^ ((d >> 1) & 3);                                      \
        vreg[dt * 2 + kt] = *(const bf16x8*)(vs + d * 32 + chunk * 8);                   \
      } }

#define SOFTMAX_PACK(IT_)                                                                \
  { int kv0s = (IT_) * 32;                                                               \
    float p[16];                                                                         \
    if ((fmask >> (IT_)) & 1ull) {                                                       \
      _Pragma("unroll") for (int r = 0; r < 16; ++r) p[r] = sv[r];                       \
    } else {                                                                             \
      _Pragma("unroll") for (int g2 = 0; g2 < 4; ++g2) {                                 \
        f32x4 bb = *(const f32x4*)(biasLds + kv0s + g2 * 8 + hi * 4);                    \
        _Pragma("unroll") for (int j = 0; j < 4; ++j)                                    \
          p[g2 * 4 + j] = sv[g2 * 4 + j] + bb[j];                                        \
      }                                                                                  \
    }                                                                                    \
    float a0 = fmaxf(fmaxf(p[0], p[1]), fmaxf(p[2], p[3]));                              \
    float a1 = fmaxf(fmaxf(p[4], p[5]), fmaxf(p[6], p[7]));                              \
    float a2 = fmaxf(fmaxf(p[8], p[9]), fmaxf(p[10], p[11]));                            \
    float a3 = fmaxf(fmaxf(p[12], p[13]), fmaxf(p[14], p[15]));                          \
    float rmx = fmaxf(fmaxf(a0, a1), fmaxf(a2, a3));                                     \
    rmx = fmaxf(rmx, __shfl_xor(rmx, 32));                                               \
    if (__any(rmx > m_ + 12.f)) {                                                        \
      float mn = fmaxf(m_, rmx);                                                         \
      float al = exp2f(m_ - mn);                                                         \
      m_ = mn; lp *= al;                                                                 \
      _Pragma("unroll") for (int dt = 0; dt < 4; ++dt)                                   \
        _Pragma("unroll") for (int r = 0; r < 16; ++r) acc[dt][r] *= al;                 \
    }                                                                                    \
    _Pragma("unroll") for (int r = 0; r < 16; ++r) p[r] = exp2f(p[r] - m_);              \
    lp += (((p[0] + p[1]) + (p[2] + p[3])) + ((p[4] + p[5]) + (p[6] + p[7])))            \
        + (((p[8] + p[9]) + (p[10] + p[11])) + ((p[12] + p[13]) + (p[14] + p[15])));     \
    _Pragma("unroll") for (int kt = 0; kt < 2; ++kt) {                                   \
      unsigned Aw = cvt_pk_bf16(p[kt * 8 + 0], p[kt * 8 + 1]);                           \
      unsigned Bw = cvt_pk_bf16(p[kt * 8 + 2], p[kt * 8 + 3]);                           \
      unsigned Cw = cvt_pk_bf16(p[kt * 8 + 4], p[kt * 8 + 5]);                           \
      unsigned Dw = cvt_pk_bf16(p[kt * 8 + 6], p[kt * 8 + 7]);                           \
      asm volatile("v_permlane32_swap_b32 %0, %1" : "+v"(Aw), "+v"(Cw));                 \
      asm volatile("v_permlane32_swap_b32 %0, %1" : "+v"(Bw), "+v"(Dw));                 \
      uint4v uu; uu.x = Aw; uu.y = Bw; uu.z = Cw; uu.w = Dw;                             \
      pfv[kt] = __builtin_bit_cast(bf16x8, uu);                                          \
    } }

  // Q fragments: B-operand, lane: col=q=ql, k-slice (d) = kc*16 + hi*8
  bf16x8 qf[8];
#pragma unroll
  for (int kc = 0; kc < 8; ++kc)
    qf[kc] = *(const bf16x8*)(Q + (size_t)(q0 + ql) * HD + kc * 16 + hi * 8);

  for (int i = t; i < 2048; i += 256) biasLds[i] = mk[i] ? 0.f : NEG;
  STAGE_KV(0, 0);
  __syncthreads();
  if (t < 64) {
    int ok = 1;
    for (int j = 0; j < 32; ++j) ok &= (biasLds[t * 32 + j] == 0.f) ? 1 : 0;
    flagsLds[t] = ok;
  }
  __syncthreads();
  unsigned long long fmask = __ballot(flagsLds[lane] != 0);

  f32x16 acc[4] = {};
  float m_ = NEG, lp = 0.f;
  f32x16 sv;
  bf16x8 pfv[2];
  bf16x8 vreg[8];

  // ---- iter 0 (peeled: no PV yet) ----
  QK_PHASE(0);
  STAGE_KV(1, 32);
  SOFTMAX_PACK(0);
  LOADV(0);
  __syncthreads();

  for (int it = 1; it < 64; ++it) {
    int cur = it & 1;
    QK_PHASE(cur);
    if (it < 63) STAGE_KV(cur ^ 1, it * 32 + 32);
    PV_PHASE();        // tile it-1, from registers (vreg/pfv)
    LOADV(cur);        // V(it) -> regs for next iter's PV
    SOFTMAX_PACK(it);  // overlaps MFMA tail; rewrites pfv for next PV
    __syncthreads();   // drains prefetch vmcnt + buffer swap
  }
  PV_PHASE();          // tail: tile 63

  // final l: combine the two k-halves, then normalize + write
  lp += __shfl_xor(lp, 32);
  float inv = 1.f / lp;
  size_t orow = (size_t)(b * 2048 + q0 + ql) * 2048 + h * 128;
#pragma unroll
  for (int dt = 0; dt < 4; ++dt)
#pragma unroll
    for (int g2 = 0; g2 < 4; ++g2) {
      f32x4 v;
      v[0] = acc[dt][g2 * 4 + 0] * inv;
      v[1] = acc[dt][g2 * 4 + 1] * inv;
      v[2] = acc[dt][g2 * 4 + 2] * inv;
      v[3] = acc[dt][g2 * 4 + 3] * inv;
      int d = dt * 32 + g2 * 8 + hi * 4;
      *(f32x4*)(out + orow + d) = v;
    }
#undef STAGE_KV
#undef QK_PHASE
#undef PV_PHASE
#undef LOADV
#undef SOFTMAX_PACK
}

// ---------------- launch ----------------

extern "C" void kernel_launch(void* const* d_in, const int* in_sizes, int n_in,
                              void* d_out, int out_size, void* d_ws, size_t ws_size,
                              hipStream_t stream) {
  const float* x = (const float*)d_in[0];
  const float* W = (const float*)d_in[1];
  const float* bias = (const float*)d_in[2];
  const void* mask = d_in[3];
  float* out = (float*)d_out;

  char* ws = (char*)d_ws;
  short* xb = (short*)(ws);
  short* wt = (short*)(ws + 16777216);
  short* qws = (short*)(ws + 41943040);
  short* kws = (short*)(ws + 58720256);
  short* vtws = (short*)(ws + 75497472);
  unsigned char* maskb = (unsigned char*)(ws + 92274688);

  convert_x_kernel<<<dim3(2048), dim3(256), 0, stream>>>(x, xb, 2 * 2048 * 2048);
  transpose_w_kernel<<<dim3(192, 64), dim3(32, 8), 0, stream>>>(W, wt);
  mask_norm_kernel<<<dim3(1), dim3(256), 0, stream>>>((const unsigned*)mask, maskb, 2 * 2048);
  qkv_gemm_kernel<<<dim3(384), dim3(512), 0, stream>>>(xb, wt, bias, qws, kws, vtws);
  attn_kernel<<<dim3(512), dim3(256), 0, stream>>>(qws, kws, vtws, maskb, out);
}